// Round 5
// baseline (182.954 us; speedup 1.0000x reference)
//
#include <hip/hip_runtime.h>

// CoordinateLoss: masked Kabsch (Horn quaternion) + Huber loss.
// B=256, S=16384, fp32 coords, int32 mask.
//
// R14: DESIGN-TO-128-VGPR. R10+R13 post-mortems: allocator hard-caps this
// kernel at 128 VGPR (launch_bounds(512,2) AND waves_per_eu(2,2) both
// ignored; spills 21.6/45.6 MB). So stop fighting: TPB=1024, PPT=16 ->
// payload = 96 floats = the float4 LOAD DESTINATIONS themselves (Pq[12],
// Tq[12], no AoS->SoA copies; components extracted with compile-time
// indices, SROA keeps arrays in regs). Peak live ~122 < 128. 16 waves/CU
// @128 VGPR = full pool. One clean 117MB logical pass, zero phase-3 reads.
// History: R12 nt loads bypass L2+L3 (HBM read wall ~1.9 TB/s) REVERTED;
// R11 both walls bind (logical ~2.9 TB/s); R9 single-pass wall ~41us;
// R8 pattern-insensitive; R5 power-iter on N/fro only.

#define NB 256       // batches == blocks
#define NS 16384     // points per batch
#define TPB 1024     // threads per block (16 waves)
#define PPT 16       // points per thread; TPB*PPT == NS
#define NQ (PPT * 3 / 4)   // 12 float4 per tensor per thread
#define NW (TPB / 64)      // 16 waves

__device__ __forceinline__ float wave_sum(float v) {
#pragma unroll
    for (int o = 32; o > 0; o >>= 1) v += __shfl_xor(v, o, 64);
    return v;
}

__device__ __forceinline__ float huber(float d) {
    float a = fabsf(d);
    return a < 1.f ? 0.5f * d * d : a - 0.5f;
}

// Compile-time component extract (c is a constant after unroll; switch folds;
// keeps float4 arrays SROA-promoted to registers -- no scratch).
__device__ __forceinline__ float f4c(const float4& v, int c) {
    switch (c & 3) {
        case 0: return v.x;
        case 1: return v.y;
        case 2: return v.z;
        default: return v.w;
    }
}
#define PX(k) f4c(Pq[(3*(k)  ) >> 2], (3*(k)  ) & 3)
#define PY(k) f4c(Pq[(3*(k)+1) >> 2], (3*(k)+1) & 3)
#define PZ(k) f4c(Pq[(3*(k)+2) >> 2], (3*(k)+2) & 3)
#define TXc(k) f4c(Tq[(3*(k)  ) >> 2], (3*(k)  ) & 3)
#define TYc(k) f4c(Tq[(3*(k)+1) >> 2], (3*(k)+1) & 3)
#define TZc(k) f4c(Tq[(3*(k)+2) >> 2], (3*(k)+2) & 3)

// One block per batch; 16 waves/CU @ <=128 VGPR fills the register pool.
__global__ __launch_bounds__(TPB)
__attribute__((amdgpu_waves_per_eu(4, 4)))
void fused_kernel(
    const float* __restrict__ pred, const float* __restrict__ tgt,
    const int* __restrict__ mask,
    float* __restrict__ bl, float* __restrict__ bc)
{
    const int b = blockIdx.x, tid = threadIdx.x;
    const long base = (long)b * NS + (long)tid * PPT;
    const float4* p4 = reinterpret_cast<const float4*>(pred + base * 3);
    const float4* t4 = reinterpret_cast<const float4*>(tgt + base * 3);
    const int4*   m4 = reinterpret_cast<const int4*>(mask + base);

    // Payload == load destinations. 24 float4 = 96 VGPR, no copies.
    float4 Pq[NQ], Tq[NQ];
    unsigned int mbits = 0u;

#pragma unroll
    for (int q = 0; q < NQ; ++q) Pq[q] = p4[q];
#pragma unroll
    for (int q = 0; q < NQ; ++q) Tq[q] = t4[q];
#pragma unroll
    for (int g = 0; g < PPT / 4; ++g) {
        const int4 mm = m4[g];
        mbits |= (mm.x ? 1u : 0u) << (4*g + 0);
        mbits |= (mm.y ? 1u : 0u) << (4*g + 1);
        mbits |= (mm.z ? 1u : 0u) << (4*g + 2);
        mbits |= (mm.w ? 1u : 0u) << (4*g + 3);
    }

    float acc[16];
#pragma unroll
    for (int i = 0; i < 16; ++i) acc[i] = 0.f;
#pragma unroll
    for (int k = 0; k < PPT; ++k) {
        const float mk = (float)((mbits >> k) & 1u);
        const float px = mk * PX(k), py = mk * PY(k), pz = mk * PZ(k);
        const float tx = TXc(k), ty = TYc(k), tz = TZc(k);
        acc[0] += mk;
        acc[1] += px;       acc[2] += py;       acc[3] += pz;
        acc[4] += mk * tx;  acc[5] += mk * ty;  acc[6] += mk * tz;
        acc[7]  += px * tx; acc[8]  += px * ty; acc[9]  += px * tz;
        acc[10] += py * tx; acc[11] += py * ty; acc[12] += py * tz;
        acc[13] += pz * tx; acc[14] += pz * ty; acc[15] += pz * tz;
    }

#pragma unroll
    for (int i = 0; i < 16; ++i) acc[i] = wave_sum(acc[i]);

    __shared__ float red[NW][16];
    __shared__ float Ssum[16];
    __shared__ float C[13];
    const int wave = tid >> 6, lane = tid & 63;
    if (lane == 0) {
#pragma unroll
        for (int i = 0; i < 16; ++i) red[wave][i] = acc[i];
    }
    __syncthreads();
    if (tid < 16) {
        float s = 0.f;
#pragma unroll
        for (int w = 0; w < NW; ++w) s += red[w][tid];
        Ssum[tid] = s;
    }
    __syncthreads();

    if (tid == 0) {
        const float cnt = Ssum[0];
        const float inv = 1.f / cnt;
        const float cpx = Ssum[1]*inv, cpy = Ssum[2]*inv, cpz = Ssum[3]*inv;
        const float ctx = Ssum[4]*inv, cty = Ssum[5]*inv, ctz = Ssum[6]*inv;
        const float Sxx = Ssum[7]  - cnt*cpx*ctx;
        const float Sxy = Ssum[8]  - cnt*cpx*cty;
        const float Sxz = Ssum[9]  - cnt*cpx*ctz;
        const float Syx = Ssum[10] - cnt*cpy*ctx;
        const float Syy = Ssum[11] - cnt*cpy*cty;
        const float Syz = Ssum[12] - cnt*cpy*ctz;
        const float Szx = Ssum[13] - cnt*cpz*ctx;
        const float Szy = Ssum[14] - cnt*cpz*cty;
        const float Szz = Ssum[15] - cnt*cpz*ctz;
        // Horn's 4x4 N: max-eigvec quaternion == Kabsch R with det(+1) fix.
        float N00 =  Sxx + Syy + Szz;
        float N01 =  Syz - Szy;
        float N02 =  Szx - Sxz;
        float N03 =  Sxy - Syx;
        float N11 =  Sxx - Syy - Szz;
        float N12 =  Sxy + Syx;
        float N13 =  Szx + Sxz;
        float N22 = -Sxx + Syy - Szz;
        float N23 =  Syz + Szy;
        float N33 = -Sxx - Syy + Szz;
        const float fro = sqrtf(N00*N00 + N11*N11 + N22*N22 + N33*N33 +
              2.f*(N01*N01 + N02*N02 + N03*N03 + N12*N12 + N13*N13 + N23*N23));
        // Spectral radius of (N/fro + I) <= 2; norm every 8 iters (R5 fix).
        const float isc = 1.f / (fro + 1e-30f);
        N00*=isc; N01*=isc; N02*=isc; N03*=isc; N11*=isc;
        N12*=isc; N13*=isc; N22*=isc; N23*=isc; N33*=isc;

        float qw = 1.f, qx = 0.1f, qy = 0.2f, qz = 0.3f;
        for (int it = 0; it < 96; ++it) {
            float nw = N00*qw + N01*qx + N02*qy + N03*qz + qw;
            float nx = N01*qw + N11*qx + N12*qy + N13*qz + qx;
            float ny = N02*qw + N12*qx + N22*qy + N23*qz + qy;
            float nz = N03*qw + N13*qx + N23*qy + N33*qz + qz;
            if ((it & 7) == 7) {
                const float r = rsqrtf(nw*nw + nx*nx + ny*ny + nz*nz);
                nw *= r; nx *= r; ny *= r; nz *= r;
            }
            qw = nw; qx = nx; qy = ny; qz = nz;
        }
        const float r = rsqrtf(qw*qw + qx*qx + qy*qy + qz*qz);
        qw *= r; qx *= r; qy *= r; qz *= r;
        const float R00 = 1.f - 2.f*(qy*qy + qz*qz);
        const float R01 = 2.f*(qx*qy - qw*qz);
        const float R02 = 2.f*(qx*qz + qw*qy);
        const float R10 = 2.f*(qx*qy + qw*qz);
        const float R11 = 1.f - 2.f*(qx*qx + qz*qz);
        const float R12 = 2.f*(qy*qz - qw*qx);
        const float R20 = 2.f*(qx*qz - qw*qy);
        const float R21 = 2.f*(qy*qz + qw*qx);
        const float R22 = 1.f - 2.f*(qx*qx + qy*qy);
        C[0]=R00; C[1]=R01; C[2]=R02;
        C[3]=R10; C[4]=R11; C[5]=R12;
        C[6]=R20; C[7]=R21; C[8]=R22;
        C[9]  = ctx - (R00*cpx + R01*cpy + R02*cpz);
        C[10] = cty - (R10*cpx + R11*cpy + R12*cpz);
        C[11] = ctz - (R20*cpx + R21*cpy + R22*cpz);
        C[12] = cnt;
    }
    __syncthreads();

    // ---- loss: fully register-resident (zero global reads) ----
    const float C0=C[0], C1=C[1], C2=C[2], C3=C[3], C4=C[4],  C5=C[5];
    const float C6=C[6], C7=C[7], C8=C[8], C9=C[9], C10=C[10], C11=C[11];
    float ls = 0.f;
#pragma unroll
    for (int k = 0; k < PPT; ++k) {
        const float mk = (float)((mbits >> k) & 1u);
        const float px = PX(k), py = PY(k), pz = PZ(k);
        const float ax = C0*px + C1*py + C2*pz + C9;
        const float ay = C3*px + C4*py + C5*pz + C10;
        const float az = C6*px + C7*py + C8*pz + C11;
        ls += mk * (huber(ax - TXc(k)) + huber(ay - TYc(k)) +
                    huber(az - TZc(k)));
    }
    ls = wave_sum(ls);
    __shared__ float redl[NW];
    if (lane == 0) redl[wave] = ls;
    __syncthreads();
    if (tid == 0) {
        float t = 0.f;
#pragma unroll
        for (int w = 0; w < NW; ++w) t += redl[w];
        bl[b] = t;
        bc[b] = C[12];
    }
}

// ---- final scalar = sum(bl) / sum(bc) over 256 batches ----
__global__ __launch_bounds__(NB) void final_kernel(
    const float* __restrict__ bl, const float* __restrict__ bc,
    float* __restrict__ out)
{
    const int tid = threadIdx.x;
    float ls = bl[tid];
    float cs = bc[tid];
    ls = wave_sum(ls);
    cs = wave_sum(cs);
    __shared__ float rl[4], rc[4];
    const int wave = tid >> 6, lane = tid & 63;
    if (lane == 0) { rl[wave] = ls; rc[wave] = cs; }
    __syncthreads();
    if (tid == 0)
        out[0] = (rl[0]+rl[1]+rl[2]+rl[3]) / (rc[0]+rc[1]+rc[2]+rc[3]);
}

extern "C" void kernel_launch(void* const* d_in, const int* in_sizes, int n_in,
                              void* d_out, int out_size, void* d_ws, size_t ws_size,
                              hipStream_t stream) {
    const float* pred = (const float*)d_in[0];
    const float* tgt  = (const float*)d_in[1];
    const int*   mask = (const int*)d_in[2];
    float* out = (float*)d_out;

    // ws layout (floats): bl[256] | bc[256]
    float* bl = (float*)d_ws;
    float* bc = bl + NB;

    fused_kernel<<<NB, TPB, 0, stream>>>(pred, tgt, mask, bl, bc);
    final_kernel<<<1, NB, 0, stream>>>(bl, bc, out);
}

// Round 6
// 160.459 us; speedup vs baseline: 1.1402x; 1.1402x over previous
//
#include <hip/hip_runtime.h>
#include <hip/hip_fp16.h>

// CoordinateLoss: masked Kabsch (Horn quaternion) + Huber loss.
// B=256, S=16384, fp32 coords, int32 mask.
//
// R15: FP16-PACKED PAYLOAD, R11 register shape. Allocator facts (R10/R13/
// R14): occupancy hints are min-only; backend picks 128 (TPB=512) or even
// 64 (TPB=1024) VGPRs and scratch-spills anything bigger. Only clean run:
// R11 (TPB=512, 96-float payload + 16 acc -> exactly 128 VGPR, 0 spill).
// So: keep the 96-reg payload but pack BOTH p and T into it as 6x fp16
// (3x __half2/point). Covariance/solve stay exact fp32 (phase 1 temps);
// phase 3 is fully in-register -> the 50MB L3-missing tgt re-read (R11's
// +17us) is gone. fp16 loss-input error ~3e-4/elem, random-sign -> ~4e-7
// in final scalar. Walls (R11/R12/R14): HBM read pinned ~1.9 TB/s,
// logical ~2.9 TB/s; single-pass floor ~41us.
// History: R12 nt bypasses L2+L3 REVERTED; R9 wall occupancy-insensitive;
// R8 pattern-insensitive; R5 power-iter on N/fro only.

#define NB 256       // batches == blocks
#define NS 16384     // points per batch
#define TPB 512      // threads per block (8 waves)
#define PPT 32       // points per thread; TPB*PPT == NS
#define NW (TPB / 64)

__device__ __forceinline__ float wave_sum(float v) {
#pragma unroll
    for (int o = 32; o > 0; o >>= 1) v += __shfl_xor(v, o, 64);
    return v;
}

__device__ __forceinline__ float huber(float d) {
    float a = fabsf(d);
    return a < 1.f ? 0.5f * d * d : a - 0.5f;
}

// One block per batch; same attribute set as R11 (the only proven
// no-spill configuration: VGPR=128, WRITE_SIZE=16KB).
__global__ __launch_bounds__(TPB)
__attribute__((amdgpu_waves_per_eu(2, 2)))
void fused_kernel(
    const float* __restrict__ pred, const float* __restrict__ tgt,
    const int* __restrict__ mask,
    float* __restrict__ bl, float* __restrict__ bc)
{
    const int b = blockIdx.x, tid = threadIdx.x;
    const long base = (long)b * NS + (long)tid * PPT;
    const float4* p4 = reinterpret_cast<const float4*>(pred + base * 3);
    const float4* t4 = reinterpret_cast<const float4*>(tgt + base * 3);
    const int4*   m4 = reinterpret_cast<const int4*>(mask + base);

    // Persistent payload: 3 __half2 per point = 96 VGPR total (== R11's
    // proven footprint), holding UNMASKED (px,py|pz,tx|ty,tz) in fp16.
    // Mask lives in mbits; covariance uses exact fp32 load temps.
    __half2 H0[PPT], H1[PPT], H2[PPT];
    unsigned int mbits = 0u;

    float acc[16];
#pragma unroll
    for (int i = 0; i < 16; ++i) acc[i] = 0.f;

#pragma unroll
    for (int g = 0; g < PPT / 4; ++g) {
        const float4 pA = p4[3*g], pB = p4[3*g+1], pC = p4[3*g+2];
        const float4 tA = t4[3*g], tB = t4[3*g+1], tC = t4[3*g+2];
        const int4 mm = m4[g];
        const float P[4][3] = {{pA.x,pA.y,pA.z},{pA.w,pB.x,pB.y},
                               {pB.z,pB.w,pC.x},{pC.y,pC.z,pC.w}};
        const float T[4][3] = {{tA.x,tA.y,tA.z},{tA.w,tB.x,tB.y},
                               {tB.z,tB.w,tC.x},{tC.y,tC.z,tC.w}};
        const int mi[4] = {mm.x, mm.y, mm.z, mm.w};
#pragma unroll
        for (int k = 0; k < 4; ++k) {
            const int idx = g * 4 + k;
            const float mk = mi[k] ? 1.f : 0.f;
            mbits |= (mi[k] ? 1u : 0u) << idx;
            // pack payload (unmasked, fp16)
            H0[idx] = __floats2half2_rn(P[k][0], P[k][1]);
            H1[idx] = __floats2half2_rn(P[k][2], T[k][0]);
            H2[idx] = __floats2half2_rn(T[k][1], T[k][2]);
            // exact fp32 covariance accumulation
            const float px = mk * P[k][0], py = mk * P[k][1], pz = mk * P[k][2];
            acc[0] += mk;
            acc[1] += px;            acc[2] += py;            acc[3] += pz;
            acc[4] += mk * T[k][0];  acc[5] += mk * T[k][1];  acc[6] += mk * T[k][2];
            acc[7]  += px * T[k][0]; acc[8]  += px * T[k][1]; acc[9]  += px * T[k][2];
            acc[10] += py * T[k][0]; acc[11] += py * T[k][1]; acc[12] += py * T[k][2];
            acc[13] += pz * T[k][0]; acc[14] += pz * T[k][1]; acc[15] += pz * T[k][2];
        }
    }

#pragma unroll
    for (int i = 0; i < 16; ++i) acc[i] = wave_sum(acc[i]);

    __shared__ float red[NW][16];
    __shared__ float Ssum[16];
    __shared__ float C[13];
    const int wave = tid >> 6, lane = tid & 63;
    if (lane == 0) {
#pragma unroll
        for (int i = 0; i < 16; ++i) red[wave][i] = acc[i];
    }
    __syncthreads();
    if (tid < 16) {
        float s = 0.f;
#pragma unroll
        for (int w = 0; w < NW; ++w) s += red[w][tid];
        Ssum[tid] = s;
    }
    __syncthreads();

    if (tid == 0) {
        const float cnt = Ssum[0];
        const float inv = 1.f / cnt;
        const float cpx = Ssum[1]*inv, cpy = Ssum[2]*inv, cpz = Ssum[3]*inv;
        const float ctx = Ssum[4]*inv, cty = Ssum[5]*inv, ctz = Ssum[6]*inv;
        const float Sxx = Ssum[7]  - cnt*cpx*ctx;
        const float Sxy = Ssum[8]  - cnt*cpx*cty;
        const float Sxz = Ssum[9]  - cnt*cpx*ctz;
        const float Syx = Ssum[10] - cnt*cpy*ctx;
        const float Syy = Ssum[11] - cnt*cpy*cty;
        const float Syz = Ssum[12] - cnt*cpy*ctz;
        const float Szx = Ssum[13] - cnt*cpz*ctx;
        const float Szy = Ssum[14] - cnt*cpz*cty;
        const float Szz = Ssum[15] - cnt*cpz*ctz;
        // Horn's 4x4 N: max-eigvec quaternion == Kabsch R with det(+1) fix.
        float N00 =  Sxx + Syy + Szz;
        float N01 =  Syz - Szy;
        float N02 =  Szx - Sxz;
        float N03 =  Sxy - Syx;
        float N11 =  Sxx - Syy - Szz;
        float N12 =  Sxy + Syx;
        float N13 =  Szx + Sxz;
        float N22 = -Sxx + Syy - Szz;
        float N23 =  Syz + Szy;
        float N33 = -Sxx - Syy + Szz;
        const float fro = sqrtf(N00*N00 + N11*N11 + N22*N22 + N33*N33 +
              2.f*(N01*N01 + N02*N02 + N03*N03 + N12*N12 + N13*N13 + N23*N23));
        // Spectral radius of (N/fro + I) <= 2; norm every 8 iters (R5 fix).
        const float isc = 1.f / (fro + 1e-30f);
        N00*=isc; N01*=isc; N02*=isc; N03*=isc; N11*=isc;
        N12*=isc; N13*=isc; N22*=isc; N23*=isc; N33*=isc;

        float qw = 1.f, qx = 0.1f, qy = 0.2f, qz = 0.3f;
        for (int it = 0; it < 96; ++it) {
            float nw = N00*qw + N01*qx + N02*qy + N03*qz + qw;
            float nx = N01*qw + N11*qx + N12*qy + N13*qz + qx;
            float ny = N02*qw + N12*qx + N22*qy + N23*qz + qy;
            float nz = N03*qw + N13*qx + N23*qy + N33*qz + qz;
            if ((it & 7) == 7) {
                const float r = rsqrtf(nw*nw + nx*nx + ny*ny + nz*nz);
                nw *= r; nx *= r; ny *= r; nz *= r;
            }
            qw = nw; qx = nx; qy = ny; qz = nz;
        }
        const float r = rsqrtf(qw*qw + qx*qx + qy*qy + qz*qz);
        qw *= r; qx *= r; qy *= r; qz *= r;
        const float R00 = 1.f - 2.f*(qy*qy + qz*qz);
        const float R01 = 2.f*(qx*qy - qw*qz);
        const float R02 = 2.f*(qx*qz + qw*qy);
        const float R10 = 2.f*(qx*qy + qw*qz);
        const float R11 = 1.f - 2.f*(qx*qx + qz*qz);
        const float R12 = 2.f*(qy*qz - qw*qx);
        const float R20 = 2.f*(qx*qz - qw*qy);
        const float R21 = 2.f*(qy*qz + qw*qx);
        const float R22 = 1.f - 2.f*(qx*qx + qy*qy);
        C[0]=R00; C[1]=R01; C[2]=R02;
        C[3]=R10; C[4]=R11; C[5]=R12;
        C[6]=R20; C[7]=R21; C[8]=R22;
        C[9]  = ctx - (R00*cpx + R01*cpy + R02*cpz);
        C[10] = cty - (R10*cpx + R11*cpy + R12*cpz);
        C[11] = ctz - (R20*cpx + R21*cpy + R22*cpz);
        C[12] = cnt;
    }
    __syncthreads();

    // ---- loss: fully register-resident (fp16 payload, zero global reads) ----
    const float C0=C[0], C1=C[1], C2=C[2], C3=C[3], C4=C[4],  C5=C[5];
    const float C6=C[6], C7=C[7], C8=C[8], C9=C[9], C10=C[10], C11=C[11];
    float ls = 0.f;
#pragma unroll
    for (int k = 0; k < PPT; ++k) {
        const float mk = (float)((mbits >> k) & 1u);
        const float2 f0 = __half22float2(H0[k]);   // px, py
        const float2 f1 = __half22float2(H1[k]);   // pz, tx
        const float2 f2 = __half22float2(H2[k]);   // ty, tz
        const float ax = C0*f0.x + C1*f0.y + C2*f1.x + C9;
        const float ay = C3*f0.x + C4*f0.y + C5*f1.x + C10;
        const float az = C6*f0.x + C7*f0.y + C8*f1.x + C11;
        ls += mk * (huber(ax - f1.y) + huber(ay - f2.x) + huber(az - f2.y));
    }
    ls = wave_sum(ls);
    __shared__ float redl[NW];
    if (lane == 0) redl[wave] = ls;
    __syncthreads();
    if (tid == 0) {
        float t = 0.f;
#pragma unroll
        for (int w = 0; w < NW; ++w) t += redl[w];
        bl[b] = t;
        bc[b] = C[12];
    }
}

// ---- final scalar = sum(bl) / sum(bc) over 256 batches ----
__global__ __launch_bounds__(NB) void final_kernel(
    const float* __restrict__ bl, const float* __restrict__ bc,
    float* __restrict__ out)
{
    const int tid = threadIdx.x;
    float ls = bl[tid];
    float cs = bc[tid];
    ls = wave_sum(ls);
    cs = wave_sum(cs);
    __shared__ float rl[4], rc[4];
    const int wave = tid >> 6, lane = tid & 63;
    if (lane == 0) { rl[wave] = ls; rc[wave] = cs; }
    __syncthreads();
    if (tid == 0)
        out[0] = (rl[0]+rl[1]+rl[2]+rl[3]) / (rc[0]+rc[1]+rc[2]+rc[3]);
}

extern "C" void kernel_launch(void* const* d_in, const int* in_sizes, int n_in,
                              void* d_out, int out_size, void* d_ws, size_t ws_size,
                              hipStream_t stream) {
    const float* pred = (const float*)d_in[0];
    const float* tgt  = (const float*)d_in[1];
    const int*   mask = (const int*)d_in[2];
    float* out = (float*)d_out;

    // ws layout (floats): bl[256] | bc[256]
    float* bl = (float*)d_ws;
    float* bc = bl + NB;

    fused_kernel<<<NB, TPB, 0, stream>>>(pred, tgt, mask, bl, bc);
    final_kernel<<<1, NB, 0, stream>>>(bl, bc, out);
}